// Round 2
// baseline (187.226 us; speedup 1.0000x reference)
//
#include <hip/hip_runtime.h>

typedef unsigned short u16;
typedef unsigned int   u32;
typedef __bf16 bf16x8 __attribute__((ext_vector_type(8)));
typedef float  f32x4  __attribute__((ext_vector_type(4)));
typedef float  f32x16 __attribute__((ext_vector_type(16)));
typedef u32    u32x4  __attribute__((ext_vector_type(4)));
typedef u16    u16x8  __attribute__((ext_vector_type(8)));

#define DEVINL __device__ __forceinline__

DEVINL void glds16(const void* g, void* l) {
  __builtin_amdgcn_global_load_lds((const __attribute__((address_space(1))) u32*)g,
                                   (__attribute__((address_space(3))) u32*)l, 16, 0, 0);
}

DEVINL u16 f2bf(float f) {  // RNE float->bf16 (finite inputs)
  u32 u = __builtin_bit_cast(u32, f);
  u32 r = u + 0x7fffu + ((u >> 16) & 1u);
  return (u16)(r >> 16);
}

// ---------------- weight cast+transpose: W[K][N] f32 -> Wt[N][K] bf16 ----------------
__global__ __launch_bounds__(256) void castw_k(const float* __restrict__ Wq,
                                               const float* __restrict__ Wkv,
                                               const float* __restrict__ Wo,
                                               u16* __restrict__ WqT, u16* __restrict__ WkvT,
                                               u16* __restrict__ WoT) {
  int i = blockIdx.x * 256 + threadIdx.x;
  if (i < 65536) {              // Wq 256x256
    int n = i >> 8, k = i & 255;
    WqT[i] = f2bf(Wq[k * 256 + n]);
  } else if (i < 196608) {      // Wkv 256x512
    int j = i - 65536; int n = j >> 8, k = j & 255;
    WkvT[j] = f2bf(Wkv[k * 512 + n]);
  } else {                      // Wo 256x256
    int j = i - 196608; int n = j >> 8, k = j & 255;
    WoT[j] = f2bf(Wo[k * 256 + n]);
  }
}

// ---------------- GEMM: C[M][N] = A[M][256] * Bt[N][256]^T + bias ----------------
// EPI 0: f32 out (+bias).  EPI 1: bf16 out, (acc+bias)*scale.  EPI 2: kv split to per-head K/V.
// A_F32: reg-stage f32 A with cvt; else bf16 A via global_load_lds.
template<int EPI, bool A_F32>
__global__ __launch_bounds__(256) void gemm_k(const void* __restrict__ Ap,
                                              const u16* __restrict__ Bt,
                                              const float* __restrict__ bias,
                                              void* __restrict__ Cp, void* __restrict__ C2p,
                                              int M, int N, int nmt, float scale) {
  const int K = 256;
  __shared__ __align__(16) u16 As[128 * 64];
  __shared__ __align__(16) u16 Bs[128 * 64];
  int tid = threadIdx.x, lane = tid & 63, w = tid >> 6;
  int g = lane >> 4, ln15 = lane & 15;
  int bid = blockIdx.x;
  int mt = bid % nmt, nt = bid / nmt;   // N-siblings of an A-panel land on the same XCD (nmt%8==0)
  int arow0 = mt * 128, bcol0 = nt * 128;
  int wr = w >> 1, wc = w & 1;
  f32x4 acc[4][4] = {};

  for (int kt = 0; kt < 4; ++kt) {
    if (kt) __syncthreads();
    // ---- stage A tile [128][64] bf16, XOR-swizzled 16B chunks ----
    if (A_F32) {
      const float* A = (const float*)Ap;
      #pragma unroll
      for (int i = 0; i < 4; ++i) {
        int c = i * 256 + tid; int row = c >> 3, k8 = c & 7;
        const float* src = A + (arow0 + row) * K + kt * 64 + k8 * 8;
        f32x4 f0 = *(const f32x4*)src, f1 = *(const f32x4*)(src + 4);
        u16x8 hh;
        hh[0]=f2bf(f0[0]); hh[1]=f2bf(f0[1]); hh[2]=f2bf(f0[2]); hh[3]=f2bf(f0[3]);
        hh[4]=f2bf(f1[0]); hh[5]=f2bf(f1[1]); hh[6]=f2bf(f1[2]); hh[7]=f2bf(f1[3]);
        int idx = row * 8 + (k8 ^ (row & 7));
        *(u16x8*)&As[idx * 8] = hh;
      }
    } else {
      const u16* A = (const u16*)Ap;
      #pragma unroll
      for (int i = 0; i < 4; ++i) {
        int c = i * 256 + tid; int row = c >> 3, seg = c & 7;
        const u16* src = A + (arow0 + row) * K + kt * 64 + (seg ^ (row & 7)) * 8;
        glds16(src, (char*)As + (i * 256 + w * 64) * 16);
      }
    }
    // ---- stage B tile via global_load_lds, source pre-swizzled ----
    #pragma unroll
    for (int i = 0; i < 4; ++i) {
      int c = i * 256 + tid; int row = c >> 3, seg = c & 7;
      const u16* src = Bt + (bcol0 + row) * K + kt * 64 + (seg ^ (row & 7)) * 8;
      glds16(src, (char*)Bs + (i * 256 + w * 64) * 16);
    }
    __syncthreads();
    // ---- compute ----
    #pragma unroll
    for (int kk = 0; kk < 2; ++kk) {
      bf16x8 af[4], bfr[4];
      #pragma unroll
      for (int mi = 0; mi < 4; ++mi) {
        int row = wr * 64 + mi * 16 + ln15;
        int idx = row * 8 + ((kk * 4 + g) ^ (row & 7));
        af[mi] = __builtin_bit_cast(bf16x8, *(const u32x4*)&As[idx * 8]);
      }
      #pragma unroll
      for (int ni = 0; ni < 4; ++ni) {
        int row = wc * 64 + ni * 16 + ln15;
        int idx = row * 8 + ((kk * 4 + g) ^ (row & 7));
        bfr[ni] = __builtin_bit_cast(bf16x8, *(const u32x4*)&Bs[idx * 8]);
      }
      #pragma unroll
      for (int mi = 0; mi < 4; ++mi)
        #pragma unroll
        for (int ni = 0; ni < 4; ++ni)
          acc[mi][ni] = __builtin_amdgcn_mfma_f32_16x16x32_bf16(af[mi], bfr[ni], acc[mi][ni], 0, 0, 0);
    }
  }
  // ---- epilogue ----
  #pragma unroll
  for (int mi = 0; mi < 4; ++mi) {
    #pragma unroll
    for (int ni = 0; ni < 4; ++ni) {
      int col = bcol0 + wc * 64 + ni * 16 + ln15;
      float bv = bias[col];
      #pragma unroll
      for (int r = 0; r < 4; ++r) {
        int row = arow0 + wr * 64 + mi * 16 + g * 4 + r;
        float v = acc[mi][ni][r] + bv;
        if (EPI == 0) {
          ((float*)Cp)[row * N + col] = v;
        } else if (EPI == 1) {
          ((u16*)Cp)[row * N + col] = f2bf(v * scale);
        } else {  // kv split; M=32768 = 8 batches x 4096
          int b = row >> 12, nk = row & 4095;
          if (col < 256) {
            int h = col >> 5, d = col & 31;
            ((u16*)Cp)[(((b << 3) + h) * 4096 + nk) * 32 + d] = f2bf(v);
          } else {
            int c2 = col - 256; int h = c2 >> 5, d = c2 & 31;
            ((u16*)C2p)[(((b << 3) + h) * 4096 + nk) * 32 + d] = f2bf(v);
          }
        }
      }
    }
  }
}

// ---------------- fused attention: per (b,h,qblk of 128 rows) ----------------
// Swapped QK^T (32x32x16): sT[k,q], lane owns q=lane&31.  exp2 in-register, cvt_pk +
// permlane32_swap -> PV A-frags.  V transposed into swizzled LDS at stage time.
__global__ __launch_bounds__(256) void attn_k(const u16* __restrict__ qb,
                                              const u16* __restrict__ kb,
                                              const u16* __restrict__ vb,
                                              u16* __restrict__ ob) {
  __shared__ __align__(16) u16 Ks[2][4 * 64 * 8];  // [buf][dchunk][krow][8]
  __shared__ __align__(16) u16 Vt[2][32 * 64];     // [buf][d][k] chunk-swizzled
  int tid = threadIdx.x, lane = tid & 63, w = tid >> 6;
  int hi = lane >> 5, ln31 = lane & 31;
  int bid = blockIdx.x;
  int bh = bid & 63, qblk = bid >> 6;   // qblk siblings share KV and the same XCD (64%8==0)
  int b = bh >> 3, h = bh & 7;
  const u16* khead = kb + bh * (4096 * 32);
  const u16* vhead = vb + bh * (4096 * 32);
  int qrow0 = b * 512 + qblk * 128 + w * 32;

  // Q fragments (B-operand): n=q=lane&31, k'=d = ks*16 + hi*8 + j
  bf16x8 qf[2];
  #pragma unroll
  for (int ks = 0; ks < 2; ++ks) {
    const u16* src = qb + (qrow0 + ln31) * 256 + h * 32 + ks * 16 + hi * 8;
    qf[ks] = __builtin_bit_cast(bf16x8, *(const u32x4*)src);
  }

  f32x16 O = {};
  float den = 0.f;
  int vrow = tid >> 2, vdc = tid & 3;

  auto loadV = [&](int kt) -> u32x4 {
    return *(const u32x4*)(vhead + (kt * 64 + vrow) * 32 + vdc * 8);
  };
  auto stage = [&](int buf, int kt, u32x4 vv) {
    // K: wave w stages d-chunk w (linear LDS dest, per-lane global src)
    glds16(khead + (kt * 64 + lane) * 32 + w * 8, (char*)&Ks[buf][0] + w * 64 * 16);
    // V transpose into LDS: element (k=vrow, d=vdc*8+j); chunk swizzle c' = c ^ (d&7) ^ ((d>>3)<<1)
    u16x8 us = __builtin_bit_cast(u16x8, vv);
    #pragma unroll
    for (int j = 0; j < 8; ++j) {
      int d = vdc * 8 + j;
      int cs = (vrow >> 3) ^ j ^ (vdc << 1);
      Vt[buf][d * 64 + cs * 8 + (vrow & 7)] = us[j];
    }
  };

  u32x4 vv = loadV(0);
  stage(0, 0, vv);
  vv = loadV(1);
  __syncthreads();

  for (int kt = 0; kt < 64; ++kt) {
    int buf = kt & 1;
    if (kt + 1 < 64) {
      stage(buf ^ 1, kt + 1, vv);
      vv = loadV(kt + 2 < 64 ? kt + 2 : 63);
    }
    // ---- S^T = K * Q^T ----
    f32x16 sT[2] = {};
    #pragma unroll
    for (int ks = 0; ks < 2; ++ks) {
      #pragma unroll
      for (int mt = 0; mt < 2; ++mt) {
        const u16* ka = &Ks[buf][((ks * 2 + hi) * 64 + mt * 32 + ln31) * 8];
        bf16x8 kf = __builtin_bit_cast(bf16x8, *(const u32x4*)ka);
        sT[mt] = __builtin_amdgcn_mfma_f32_32x32x16_bf16(kf, qf[ks], sT[mt], 0, 0, 0);
      }
    }
    // ---- p = 2^s, den, pack to PV A-frags ----
    u32 pa[4][4];
    #pragma unroll
    for (int mt = 0; mt < 2; ++mt) {
      float p[16];
      #pragma unroll
      for (int r = 0; r < 16; ++r) {
        p[r] = __builtin_amdgcn_exp2f(sT[mt][r]);
      }
      #pragma unroll
      for (int r = 0; r < 16; ++r) den += p[r];
      u32 pk0[4], pk1[4];
      #pragma unroll
      for (int c = 0; c < 4; ++c) {
        asm("v_cvt_pk_bf16_f32 %0, %1, %2" : "=v"(pk0[c]) : "v"(p[4*c+0]), "v"(p[4*c+1]));
        asm("v_cvt_pk_bf16_f32 %0, %1, %2" : "=v"(pk1[c]) : "v"(p[4*c+2]), "v"(p[4*c+3]));
      }
      u32 a0 = pk0[0], b0 = pk0[1];
      asm("v_permlane32_swap_b32 %0, %1" : "+v"(a0), "+v"(b0));
      u32 a1 = pk1[0], b1 = pk1[1];
      asm("v_permlane32_swap_b32 %0, %1" : "+v"(a1), "+v"(b1));
      u32 a2 = pk0[2], b2 = pk0[3];
      asm("v_permlane32_swap_b32 %0, %1" : "+v"(a2), "+v"(b2));
      u32 a3 = pk1[2], b3 = pk1[3];
      asm("v_permlane32_swap_b32 %0, %1" : "+v"(a3), "+v"(b3));
      pa[mt*2+0][0] = a0; pa[mt*2+0][1] = a1; pa[mt*2+0][2] = b0; pa[mt*2+0][3] = b1;
      pa[mt*2+1][0] = a2; pa[mt*2+1][1] = a3; pa[mt*2+1][2] = b2; pa[mt*2+1][3] = b3;
    }
    // ---- O += P * V ----
    #pragma unroll
    for (int kst = 0; kst < 4; ++kst) {
      int cs = (kst * 2 + hi) ^ (ln31 & 7) ^ ((ln31 >> 3) << 1);
      const u16* va = &Vt[buf][ln31 * 64 + cs * 8];
      bf16x8 vf = __builtin_bit_cast(bf16x8, *(const u32x4*)va);
      u32x4 paw = {pa[kst][0], pa[kst][1], pa[kst][2], pa[kst][3]};
      O = __builtin_amdgcn_mfma_f32_32x32x16_bf16(__builtin_bit_cast(bf16x8, paw), vf, O, 0, 0, 0);
    }
    __syncthreads();
  }

  // ---- finalize: den across hi-halves, normalize, store bf16 ----
  den += __shfl_xor(den, 32);
  #pragma unroll
  for (int r = 0; r < 16; ++r) {
    int qr = 8 * (r >> 2) + 4 * hi + (r & 3);
    float dq = __shfl(den, qr);
    float ov = O[r] / dq;
    ob[(qrow0 + qr) * 256 + h * 32 + ln31] = f2bf(ov);
  }
}

// ---------------- host ----------------
extern "C" void kernel_launch(void* const* d_in, const int* in_sizes, int n_in,
                              void* d_out, int out_size, void* d_ws, size_t ws_size,
                              hipStream_t stream) {
  const float* state = (const float*)d_in[0];
  const float* pc    = (const float*)d_in[1];
  const float* Wq    = (const float*)d_in[2];
  const float* bq    = (const float*)d_in[3];
  const float* Wkv   = (const float*)d_in[4];
  const float* bkv   = (const float*)d_in[5];
  const float* Wo    = (const float*)d_in[6];
  const float* bo    = (const float*)d_in[7];
  char* ws = (char*)d_ws;
  u16* WqT  = (u16*)(ws);
  u16* WkvT = (u16*)(ws + 131072);
  u16* WoT  = (u16*)(ws + 393216);
  u16* qb   = (u16*)(ws + 524288);     // [4096][256] bf16, pre-scaled by SCALE*log2e
  u16* kb   = (u16*)(ws + 2621440);    // [64][4096][32] bf16
  u16* vb   = (u16*)(ws + 19398656);   // [64][4096][32] bf16
  u16* ob   = (u16*)(ws + 36175872);   // [4096][256] bf16

  castw_k<<<1024, 256, 0, stream>>>(Wq, Wkv, Wo, WqT, WkvT, WoT);
  const float QSCL = 0.17677669529663687f * 1.4426950408889634f;  // SCALE * log2(e)
  gemm_k<1, true ><<<64,   256, 0, stream>>>(state, WqT, bq, qb, nullptr, 4096, 256, 32, QSCL);
  gemm_k<2, true ><<<1024, 256, 0, stream>>>(pc, WkvT, bkv, kb, vb, 32768, 512, 256, 1.f);
  attn_k<<<256, 256, 0, stream>>>(qb, kb, vb, ob);
  gemm_k<0, false><<<64,   256, 0, stream>>>(ob, WoT, bo, d_out, nullptr, 4096, 256, 32, 1.f);
}

// Round 3
// 150.994 us; speedup vs baseline: 1.2400x; 1.2400x over previous
//
#include <hip/hip_runtime.h>

typedef unsigned short u16;
typedef unsigned int   u32;
typedef __bf16 bf16x8 __attribute__((ext_vector_type(8)));
typedef float  f32x4  __attribute__((ext_vector_type(4)));
typedef float  f32x16 __attribute__((ext_vector_type(16)));
typedef u32    u32x4  __attribute__((ext_vector_type(4)));
typedef u16    u16x8  __attribute__((ext_vector_type(8)));

#define DEVINL __device__ __forceinline__

DEVINL void glds16(const void* g, void* l) {
  __builtin_amdgcn_global_load_lds((const __attribute__((address_space(1))) u32*)g,
                                   (__attribute__((address_space(3))) u32*)l, 16, 0, 0);
}

DEVINL u16 f2bf(float f) {  // RNE float->bf16 (finite inputs)
  u32 u = __builtin_bit_cast(u32, f);
  u32 r = u + 0x7fffu + ((u >> 16) & 1u);
  return (u16)(r >> 16);
}

// ---------------- weight cast+transpose: W[K][N] f32 -> Wt[N][K] bf16 ----------------
__global__ __launch_bounds__(256) void castw_k(const float* __restrict__ Wq,
                                               const float* __restrict__ Wkv,
                                               const float* __restrict__ Wo,
                                               u16* __restrict__ WqT, u16* __restrict__ WkvT,
                                               u16* __restrict__ WoT) {
  int i = blockIdx.x * 256 + threadIdx.x;
  if (i < 65536) {              // Wq 256x256
    int n = i >> 8, k = i & 255;
    WqT[i] = f2bf(Wq[k * 256 + n]);
  } else if (i < 196608) {      // Wkv 256x512
    int j = i - 65536; int n = j >> 8, k = j & 255;
    WkvT[j] = f2bf(Wkv[k * 512 + n]);
  } else {                      // Wo 256x256
    int j = i - 196608; int n = j >> 8, k = j & 255;
    WoT[j] = f2bf(Wo[k * 256 + n]);
  }
}

// ---------------- GEMM: C[M][N] = A[M][256] * Bt[N][256]^T + bias ----------------
// EPI 0: f32 out (+bias).  EPI 1: bf16 out, (acc+bias)*scale.  EPI 2: kv split to per-head K/V.
// A_F32: reg-stage f32 A with cvt; else bf16 A via global_load_lds.
// XCDSWZ: chunk blocks per XCD so nt-siblings of an A-panel share L2 (grid%8==0, N=512).
template<int EPI, bool A_F32, bool XCDSWZ>
__global__ __launch_bounds__(256) void gemm_k(const void* __restrict__ Ap,
                                              const u16* __restrict__ Bt,
                                              const float* __restrict__ bias,
                                              void* __restrict__ Cp, void* __restrict__ C2p,
                                              int M, int N, int nmt, float scale) {
  const int K = 256;
  __shared__ __align__(16) u16 As[128 * 64];
  __shared__ __align__(16) u16 Bs[128 * 64];
  int tid = threadIdx.x, lane = tid & 63, w = tid >> 6;
  int g = lane >> 4, ln15 = lane & 15;
  int bid = blockIdx.x;
  int mt, nt;
  if (XCDSWZ) {
    int u = (bid & 7) * (gridDim.x >> 3) + (bid >> 3);  // contiguous chunk per XCD
    mt = u >> 2; nt = u & 3;                            // XCD covers all nt of its mt range
  } else {
    mt = bid % nmt; nt = bid / nmt;
  }
  int arow0 = mt * 128, bcol0 = nt * 128;
  int wr = w >> 1, wc = w & 1;
  f32x4 acc[4][4] = {};

  for (int kt = 0; kt < 4; ++kt) {
    if (kt) __syncthreads();
    // ---- stage A tile [128][64] bf16, XOR-swizzled 16B chunks ----
    if (A_F32) {
      const float* A = (const float*)Ap;
      #pragma unroll
      for (int i = 0; i < 4; ++i) {
        int c = i * 256 + tid; int row = c >> 3, k8 = c & 7;
        const float* src = A + (arow0 + row) * K + kt * 64 + k8 * 8;
        f32x4 f0 = *(const f32x4*)src, f1 = *(const f32x4*)(src + 4);
        u16x8 hh;
        hh[0]=f2bf(f0[0]); hh[1]=f2bf(f0[1]); hh[2]=f2bf(f0[2]); hh[3]=f2bf(f0[3]);
        hh[4]=f2bf(f1[0]); hh[5]=f2bf(f1[1]); hh[6]=f2bf(f1[2]); hh[7]=f2bf(f1[3]);
        int idx = row * 8 + (k8 ^ (row & 7));
        *(u16x8*)&As[idx * 8] = hh;
      }
    } else {
      const u16* A = (const u16*)Ap;
      #pragma unroll
      for (int i = 0; i < 4; ++i) {
        int c = i * 256 + tid; int row = c >> 3, seg = c & 7;
        const u16* src = A + (arow0 + row) * K + kt * 64 + (seg ^ (row & 7)) * 8;
        glds16(src, (char*)As + (i * 256 + w * 64) * 16);
      }
    }
    // ---- stage B tile via global_load_lds, source pre-swizzled ----
    #pragma unroll
    for (int i = 0; i < 4; ++i) {
      int c = i * 256 + tid; int row = c >> 3, seg = c & 7;
      const u16* src = Bt + (bcol0 + row) * K + kt * 64 + (seg ^ (row & 7)) * 8;
      glds16(src, (char*)Bs + (i * 256 + w * 64) * 16);
    }
    __syncthreads();
    // ---- compute ----
    #pragma unroll
    for (int kk = 0; kk < 2; ++kk) {
      bf16x8 af[4], bfr[4];
      #pragma unroll
      for (int mi = 0; mi < 4; ++mi) {
        int row = wr * 64 + mi * 16 + ln15;
        int idx = row * 8 + ((kk * 4 + g) ^ (row & 7));
        af[mi] = __builtin_bit_cast(bf16x8, *(const u32x4*)&As[idx * 8]);
      }
      #pragma unroll
      for (int ni = 0; ni < 4; ++ni) {
        int row = wc * 64 + ni * 16 + ln15;
        int idx = row * 8 + ((kk * 4 + g) ^ (row & 7));
        bfr[ni] = __builtin_bit_cast(bf16x8, *(const u32x4*)&Bs[idx * 8]);
      }
      #pragma unroll
      for (int mi = 0; mi < 4; ++mi)
        #pragma unroll
        for (int ni = 0; ni < 4; ++ni)
          acc[mi][ni] = __builtin_amdgcn_mfma_f32_16x16x32_bf16(af[mi], bfr[ni], acc[mi][ni], 0, 0, 0);
    }
  }
  // ---- epilogue ----
  #pragma unroll
  for (int mi = 0; mi < 4; ++mi) {
    #pragma unroll
    for (int ni = 0; ni < 4; ++ni) {
      int col = bcol0 + wc * 64 + ni * 16 + ln15;
      float bv = bias[col];
      #pragma unroll
      for (int r = 0; r < 4; ++r) {
        int row = arow0 + wr * 64 + mi * 16 + g * 4 + r;
        float v = acc[mi][ni][r] + bv;
        if (EPI == 0) {
          ((float*)Cp)[row * N + col] = v;
        } else if (EPI == 1) {
          ((u16*)Cp)[row * N + col] = f2bf(v * scale);
        } else {  // kv split; M=32768 = 8 batches x 4096
          int b = row >> 12, nk = row & 4095;
          if (col < 256) {
            int h = col >> 5, d = col & 31;
            ((u16*)Cp)[(((b << 3) + h) * 4096 + nk) * 32 + d] = f2bf(v);
          } else {
            int c2 = col - 256; int h = c2 >> 5, d = c2 & 31;
            ((u16*)C2p)[(((b << 3) + h) * 4096 + nk) * 32 + d] = f2bf(v);
          }
        }
      }
    }
  }
}

// ---------------- fused attention: 16 waves = 4 q-groups x 4 K-splits ----------------
// Block = (b,h,qblk of 128 rows), 1024 threads.  Wave (q,s): 32 q-rows, keys [s*1024,(s+1)*1024).
// Each split-stream s has its own dbuf K/V LDS stream (staged by its 4 waves = 256 threads).
// Swapped QK^T (32x32x16), in-register exp2, cvt_pk+permlane32_swap -> PV A-frags.
// End: combine 4 split partials (O, den) via LDS, normalize, store.
__global__ __launch_bounds__(1024, 4) void attn_k(const u16* __restrict__ qb,
                                                  const u16* __restrict__ kb,
                                                  const u16* __restrict__ vb,
                                                  u16* __restrict__ ob) {
  __shared__ __align__(16) char smem[65536];
  int tid = threadIdx.x, lane = tid & 63, w = tid >> 6;
  int hi = lane >> 5, ln31 = lane & 31;
  int q = w & 3, s = w >> 2;
  int stid = tid & 255;                  // thread id within split-stream group
  int ws2 = (stid >> 6);                 // wave-within-stream (== q)
  int bid = blockIdx.x;
  int bh = bid & 63, qblk = bid >> 6;    // qblk siblings share KV and the same XCD (64%8==0)
  int b = bh >> 3, h = bh & 7;
  const u16* khead = kb + bh * (4096 * 32);
  const u16* vhead = vb + bh * (4096 * 32);
  int qrow0 = b * 512 + qblk * 128 + q * 32;

  u16* Ks = (u16*)smem;                  // [stream*2+buf][4 dchunk][64 krow][8]
  u16* Vt = (u16*)(smem + 32768);        // [stream*2+buf][32 d][64 k] chunk-swizzled

  // Q fragments (B-operand): n=q-col=lane&31, k'=d = ks*16 + hi*8 + j
  bf16x8 qf[2];
  #pragma unroll
  for (int ks = 0; ks < 2; ++ks) {
    const u16* src = qb + (qrow0 + ln31) * 256 + h * 32 + ks * 16 + hi * 8;
    qf[ks] = __builtin_bit_cast(bf16x8, *(const u32x4*)src);
  }

  f32x16 O = {};
  float den = 0.f;
  int vrow = stid >> 2, vdc = stid & 3;

  auto loadV = [&](int t) -> u32x4 {     // t in [0,16), tile = s*16+t
    return *(const u32x4*)(vhead + (((s * 16 + t) * 64) + vrow) * 32 + vdc * 8);
  };
  auto stage = [&](int buf, int t, u32x4 vv) {
    u16* ksb = Ks + (s * 2 + buf) * 2048;
    u16* vtb = Vt + (s * 2 + buf) * 2048;
    // K: wave ws2 stages d-chunk ws2 (linear LDS dest, per-lane global src)
    glds16(khead + (((s * 16 + t) * 64) + lane) * 32 + ws2 * 8, (char*)ksb + ws2 * 64 * 16);
    // V transpose into LDS: element (k=vrow, d=vdc*8+j); chunk swizzle c' = c ^ (d&7) ^ ((d>>3)<<1)
    u16x8 us = __builtin_bit_cast(u16x8, vv);
    #pragma unroll
    for (int j = 0; j < 8; ++j) {
      int d = vdc * 8 + j;
      int cs = (vrow >> 3) ^ j ^ (vdc << 1);
      vtb[d * 64 + cs * 8 + (vrow & 7)] = us[j];
    }
  };

  u32x4 vv = loadV(0);
  stage(0, 0, vv);
  vv = loadV(1);
  __syncthreads();

  for (int t = 0; t < 16; ++t) {
    int buf = t & 1;
    if (t + 1 < 16) {
      stage(buf ^ 1, t + 1, vv);
      vv = loadV(t + 2 < 16 ? t + 2 : 15);
    }
    const u16* ksb = Ks + (s * 2 + buf) * 2048;
    const u16* vtb = Vt + (s * 2 + buf) * 2048;
    // ---- S^T = K * Q^T ----
    f32x16 sT[2] = {};
    #pragma unroll
    for (int ks = 0; ks < 2; ++ks) {
      #pragma unroll
      for (int mt = 0; mt < 2; ++mt) {
        const u16* ka = &ksb[((ks * 2 + hi) * 64 + mt * 32 + ln31) * 8];
        bf16x8 kf = __builtin_bit_cast(bf16x8, *(const u32x4*)ka);
        sT[mt] = __builtin_amdgcn_mfma_f32_32x32x16_bf16(kf, qf[ks], sT[mt], 0, 0, 0);
      }
    }
    // ---- p = 2^s, den, pack to PV A-frags ----
    u32 pa[4][4];
    #pragma unroll
    for (int mt = 0; mt < 2; ++mt) {
      float p[16];
      #pragma unroll
      for (int r = 0; r < 16; ++r) p[r] = __builtin_amdgcn_exp2f(sT[mt][r]);
      #pragma unroll
      for (int r = 0; r < 16; ++r) den += p[r];
      u32 pk0[4], pk1[4];
      #pragma unroll
      for (int c = 0; c < 4; ++c) {
        asm("v_cvt_pk_bf16_f32 %0, %1, %2" : "=v"(pk0[c]) : "v"(p[4*c+0]), "v"(p[4*c+1]));
        asm("v_cvt_pk_bf16_f32 %0, %1, %2" : "=v"(pk1[c]) : "v"(p[4*c+2]), "v"(p[4*c+3]));
      }
      u32 a0 = pk0[0], b0 = pk0[1];
      asm("v_permlane32_swap_b32 %0, %1" : "+v"(a0), "+v"(b0));
      u32 a1 = pk1[0], b1 = pk1[1];
      asm("v_permlane32_swap_b32 %0, %1" : "+v"(a1), "+v"(b1));
      u32 a2 = pk0[2], b2 = pk0[3];
      asm("v_permlane32_swap_b32 %0, %1" : "+v"(a2), "+v"(b2));
      u32 a3 = pk1[2], b3 = pk1[3];
      asm("v_permlane32_swap_b32 %0, %1" : "+v"(a3), "+v"(b3));
      pa[mt*2+0][0] = a0; pa[mt*2+0][1] = a1; pa[mt*2+0][2] = b0; pa[mt*2+0][3] = b1;
      pa[mt*2+1][0] = a2; pa[mt*2+1][1] = a3; pa[mt*2+1][2] = b2; pa[mt*2+1][3] = b3;
    }
    // ---- O += P * V ----
    #pragma unroll
    for (int kst = 0; kst < 4; ++kst) {
      int cs = (kst * 2 + hi) ^ (ln31 & 7) ^ ((ln31 >> 3) << 1);
      const u16* va = &vtb[ln31 * 64 + cs * 8];
      bf16x8 vf = __builtin_bit_cast(bf16x8, *(const u32x4*)va);
      u32x4 paw = {pa[kst][0], pa[kst][1], pa[kst][2], pa[kst][3]};
      O = __builtin_amdgcn_mfma_f32_32x32x16_bf16(__builtin_bit_cast(bf16x8, paw), vf, O, 0, 0, 0);
    }
    __syncthreads();
  }

  // ---- combine K-split partials via LDS (reuse smem), then normalize + store ----
  float* po = (float*)smem;              // [q][s-1][lane][16] f32  (48 KB)
  float* pd = (float*)(smem + 49152);    // [q][s-1][lane]          (3 KB)
  if (s != 0) {
    int base = ((q * 3 + (s - 1)) * 64 + lane) * 16;
    #pragma unroll
    for (int r = 0; r < 16; ++r) po[base + r] = O[r];
    pd[(q * 3 + (s - 1)) * 64 + lane] = den;
  }
  __syncthreads();
  if (s == 0) {
    #pragma unroll
    for (int j = 0; j < 3; ++j) {
      int base = ((q * 3 + j) * 64 + lane) * 16;
      #pragma unroll
      for (int r = 0; r < 16; ++r) O[r] += po[base + r];
      den += pd[(q * 3 + j) * 64 + lane];
    }
    den += __shfl_xor(den, 32);
    #pragma unroll
    for (int r = 0; r < 16; ++r) {
      int qr = 8 * (r >> 2) + 4 * hi + (r & 3);
      float dq = __shfl(den, qr);
      float ov = O[r] / dq;
      ob[(qrow0 + qr) * 256 + h * 32 + ln31] = f2bf(ov);
    }
  }
}

// ---------------- host ----------------
extern "C" void kernel_launch(void* const* d_in, const int* in_sizes, int n_in,
                              void* d_out, int out_size, void* d_ws, size_t ws_size,
                              hipStream_t stream) {
  const float* state = (const float*)d_in[0];
  const float* pc    = (const float*)d_in[1];
  const float* Wq    = (const float*)d_in[2];
  const float* bq    = (const float*)d_in[3];
  const float* Wkv   = (const float*)d_in[4];
  const float* bkv   = (const float*)d_in[5];
  const float* Wo    = (const float*)d_in[6];
  const float* bo    = (const float*)d_in[7];
  char* ws = (char*)d_ws;
  u16* WqT  = (u16*)(ws);
  u16* WkvT = (u16*)(ws + 131072);
  u16* WoT  = (u16*)(ws + 393216);
  u16* qb   = (u16*)(ws + 524288);     // [4096][256] bf16, pre-scaled by SCALE*log2e
  u16* kb   = (u16*)(ws + 2621440);    // [64][4096][32] bf16
  u16* vb   = (u16*)(ws + 19398656);   // [64][4096][32] bf16
  u16* ob   = (u16*)(ws + 36175872);   // [4096][256] bf16

  castw_k<<<1024, 256, 0, stream>>>(Wq, Wkv, Wo, WqT, WkvT, WoT);
  const float QSCL = 0.17677669529663687f * 1.4426950408889634f;  // SCALE * log2(e)
  gemm_k<1, true,  false><<<64,   256, 0, stream>>>(state, WqT, bq, qb, nullptr, 4096, 256, 32, QSCL);
  gemm_k<2, true,  true ><<<1024, 256, 0, stream>>>(pc, WkvT, bkv, kb, vb, 32768, 512, 256, 1.f);
  attn_k<<<256, 1024, 0, stream>>>(qb, kb, vb, ob);
  gemm_k<0, false, false><<<64,   256, 0, stream>>>(ob, WoT, bo, d_out, nullptr, 4096, 256, 32, 1.f);
}